// Round 7
// baseline (208.363 us; speedup 1.0000x reference)
//
#include <hip/hip_runtime.h>
#include <hip/hip_bf16.h>

#define MARGIN  0.3f
#define NEG_INF -1e30f
#define POS_INF  1e30f

#define BMN 128
#define BK  32
#define NTH 256

typedef __attribute__((ext_vector_type(8))) short bf16x8;
typedef __attribute__((ext_vector_type(4))) float f32x4;

// async global->LDS, 16B per lane (dest linear in lane; source is per-lane)
#define GLOAD_LDS16(g, l) __builtin_amdgcn_global_load_lds(                      \
    (const __attribute__((address_space(1))) void*)(g),                          \
    (__attribute__((address_space(3))) void*)(l), 16, 0, 0)

// LDS byte offset for bf16 [128][32] tile, rows paired into 128B lines,
// XOR-swizzled: uniform 2-way bank alias on 16-lane b128 frag reads (free).
__device__ __forceinline__ int LDSB(int row, int kb) {
    return ((row >> 1) << 7) + ((((row & 1) << 6) | kb) ^ (((row >> 1) & 7) << 4));
}

// ---- order-preserving float <-> uint mapping for atomic max/min ----
__device__ __forceinline__ unsigned f2ord(float f) {
    unsigned u = __float_as_uint(f);
    return (u & 0x80000000u) ? ~u : (u | 0x80000000u);
}
__device__ __forceinline__ float ord2f(unsigned u) {
    unsigned b = (u & 0x80000000u) ? (u ^ 0x80000000u) : ~u;
    return __uint_as_float(b);
}
__device__ __forceinline__ unsigned short f2bf(float f) {
    unsigned u = __float_as_uint(f);
    u += 0x7fffu + ((u >> 16) & 1u);
    return (unsigned short)(u >> 16);
}

// ---- kernel 1: fp32 -> bf16 convert + row sum-of-squares + init (1 row/wave) ----
__global__ __launch_bounds__(256)
void convert_kernel(const float* __restrict__ X, int d,
                    unsigned short* __restrict__ Xb,
                    float* __restrict__ sq,
                    unsigned* __restrict__ apk,
                    unsigned* __restrict__ ank,
                    unsigned* __restrict__ done) {
    const int tid  = threadIdx.x;
    const int lane = tid & 63, wid = tid >> 6;
    if (blockIdx.x == 0 && tid == 0) *done = 0u;
    // 16 rows per block, 1 row per wave per pass, 4 passes
    for (int p = 0; p < 4; ++p) {
        int row = (int)blockIdx.x * 16 + p * 4 + wid;
        const float4* xr = (const float4*)(X + (size_t)row * d);
        float s = 0.f;
        float4 v[8];
#pragma unroll
        for (int j = 0; j < 8; ++j) v[j] = xr[lane + 64 * j];
#pragma unroll
        for (int j = 0; j < 8; ++j) {
            s += v[j].x * v[j].x + v[j].y * v[j].y + v[j].z * v[j].z + v[j].w * v[j].w;
            uint2 w;
            w.x = (unsigned)f2bf(v[j].x) | ((unsigned)f2bf(v[j].y) << 16);
            w.y = (unsigned)f2bf(v[j].z) | ((unsigned)f2bf(v[j].w) << 16);
            *(uint2*)(Xb + (size_t)row * d + (lane + 64 * j) * 4) = w;
        }
#pragma unroll
        for (int off = 32; off; off >>= 1) s += __shfl_down(s, off);
        if (lane == 0) {
            sq[row]  = s;
            apk[row] = f2ord(NEG_INF);
            ank[row] = f2ord(POS_INF);
        }
    }
}

// ---- kernel 2: MFMA Gram tile (upper-tri), dbuf BK=32, 4 blocks/CU,
//      fused mining + last-block loss reduction ----
__global__ __launch_bounds__(NTH, 4)
void mfma_tile_kernel(const unsigned short* __restrict__ Xb,
                      const int* __restrict__ tgt,
                      const float* __restrict__ sq,
                      unsigned* __restrict__ apk, unsigned* __restrict__ ank,
                      unsigned* __restrict__ done, float* __restrict__ out,
                      int n, int d) {
    __shared__ short As[2][BMN * BK];        // 2 x 8 KB, pair-swizzled image
    __shared__ short Bs[2][BMN * BK];        // 2 x 8 KB
    __shared__ float srow_s[BMN], scol_s[BMN];
    __shared__ int   trow_s[BMN], tcol_s[BMN];

    const int nt = n / BMN;
    const int total = nt * (nt + 1) / 2;     // 528, divisible by 8
    const int cpx = total / 8;
    int b = (blockIdx.x % 8) * cpx + blockIdx.x / 8;
    int bi = 0, rem = b;
    for (; bi < nt; ++bi) { int cnt = nt - bi; if (rem < cnt) break; rem -= cnt; }
    const int bj = bi + rem;
    const int row0 = bi * BMN, col0 = bj * BMN;

    const int tid  = threadIdx.x;
    const int lane = tid & 63, wid = tid >> 6;
    const int wr = wid >> 1, wc = wid & 1;   // 2x2 waves, each 64x64 quadrant
    const int lr = lane & 15, lh = lane >> 4;

    if (tid < BMN) { srow_s[tid] = sq[row0 + tid]; trow_s[tid] = tgt[row0 + tid]; }
    else { int j = tid - BMN; scol_s[j] = sq[col0 + j]; tcol_s[j] = tgt[col0 + j]; }

    f32x4 acc[4][4];
#pragma unroll
    for (int m = 0; m < 4; ++m)
#pragma unroll
        for (int nn = 0; nn < 4; ++nn) acc[m][nn] = (f32x4){0.f, 0.f, 0.f, 0.f};

    const size_t dstride = (size_t)d * 2;    // bf16 row stride in bytes
    const char* Arow = (const char*)Xb + (size_t)row0 * dstride;
    const char* Brow = (const char*)Xb + (size_t)col0 * dstride;

    // dest linear in lane; source pre-inverse-swizzled so LDS image matches LDSB()
#define STAGE(sel, kbyte)                                                        \
    do {                                                                         \
        _Pragma("unroll")                                                        \
        for (int it = 0; it < 2; ++it) {                                         \
            int p  = it * 4096 + tid * 16;                                       \
            int pr = p >> 7, q = p & 127;                                        \
            int u  = q ^ ((pr & 7) << 4);                                        \
            int r  = pr * 2 + (u >> 6);                                          \
            int kb = u & 63;                                                     \
            GLOAD_LDS16(Arow + (size_t)r * dstride + (kbyte) + kb,               \
                        (char*)As[sel] + p);                                     \
        }                                                                        \
        _Pragma("unroll")                                                        \
        for (int it = 0; it < 2; ++it) {                                         \
            int p  = it * 4096 + tid * 16;                                       \
            int pr = p >> 7, q = p & 127;                                        \
            int u  = q ^ ((pr & 7) << 4);                                        \
            int r  = pr * 2 + (u >> 6);                                          \
            int kb = u & 63;                                                     \
            GLOAD_LDS16(Brow + (size_t)r * dstride + (kbyte) + kb,               \
                        (char*)Bs[sel] + p);                                     \
        }                                                                        \
    } while (0)

    const int nt_k = d / BK;                 // 64 steps
    STAGE(0, 0);
    __syncthreads();                         // drain prologue + srow/scol visible
    int cur = 0;
    for (int t = 0; t < nt_k; ++t) {
        if (t + 1 < nt_k) STAGE(cur ^ 1, (t + 1) * (BK * 2));  // prefetch next
        {
            bf16x8 af[4], bfr[4];
            const int kb2 = lh * 16;         // byte offset along k (0..48)
#pragma unroll
            for (int m = 0; m < 4; ++m) {
                int ar = wr * 64 + m * 16 + lr;
                af[m] = *(bf16x8*)((char*)As[cur] + LDSB(ar, kb2));
            }
#pragma unroll
            for (int nn = 0; nn < 4; ++nn) {
                int br = wc * 64 + nn * 16 + lr;
                bfr[nn] = *(bf16x8*)((char*)Bs[cur] + LDSB(br, kb2));
            }
#pragma unroll
            for (int m = 0; m < 4; ++m)
#pragma unroll
                for (int nn = 0; nn < 4; ++nn)
                    acc[m][nn] = __builtin_amdgcn_mfma_f32_16x16x32_bf16(
                        af[m], bfr[nn], acc[m][nn], 0, 0, 0);
        }
        __syncthreads();                     // one barrier per K-step
        cur ^= 1;
    }
#undef STAGE

    // ---- epilogue: dist = sq_i + sq_j - 2*ip; mine rows AND cols ----
    float sc[4]; int tc[4];
#pragma unroll
    for (int nn = 0; nn < 4; ++nn) {
        int cl = wc * 64 + nn * 16 + lr;
        sc[nn] = scol_s[cl]; tc[nn] = tcol_s[cl];
    }
    float rap[4][4], ran[4][4], cap[4], can[4];
#pragma unroll
    for (int nn = 0; nn < 4; ++nn) { cap[nn] = NEG_INF; can[nn] = POS_INF; }
#pragma unroll
    for (int m = 0; m < 4; ++m)
#pragma unroll
        for (int j = 0; j < 4; ++j) { rap[m][j] = NEG_INF; ran[m][j] = POS_INF; }

#pragma unroll
    for (int m = 0; m < 4; ++m) {
#pragma unroll
        for (int j = 0; j < 4; ++j) {
            int rl = wr * 64 + m * 16 + lh * 4 + j;
            float sr = srow_s[rl];
            int   tr = trow_s[rl];
#pragma unroll
            for (int nn = 0; nn < 4; ++nn) {
                float dist = sr + sc[nn] - 2.0f * acc[m][nn][j];
                bool same = (tr == tc[nn]);
                float apv = same ? dist : NEG_INF;
                float anv = same ? POS_INF : dist;
                rap[m][j] = fmaxf(rap[m][j], apv);
                ran[m][j] = fminf(ran[m][j], anv);
                cap[nn]   = fmaxf(cap[nn], apv);
                can[nn]   = fminf(can[nn], anv);
            }
        }
    }
    // row mining: reduce over cols (lane bits 0..3), atomic per row
#pragma unroll
    for (int m = 0; m < 4; ++m) {
#pragma unroll
        for (int j = 0; j < 4; ++j) {
            float a = rap[m][j], v = ran[m][j];
#pragma unroll
            for (int off = 1; off < 16; off <<= 1) {
                a = fmaxf(a, __shfl_xor(a, off));
                v = fminf(v, __shfl_xor(v, off));
            }
            if (lr == 0) {
                int gr = row0 + wr * 64 + m * 16 + lh * 4 + j;
                atomicMax(&apk[gr], f2ord(a));
                atomicMin(&ank[gr], f2ord(v));
            }
        }
    }
    // col mining: reduce over rows (lane bits 4..5), atomic per col
#pragma unroll
    for (int nn = 0; nn < 4; ++nn) {
        float a = cap[nn], v = can[nn];
#pragma unroll
        for (int off = 16; off < 64; off <<= 1) {
            a = fmaxf(a, __shfl_xor(a, off));
            v = fminf(v, __shfl_xor(v, off));
        }
        if (lane < 16) {
            int gc = col0 + wc * 64 + nn * 16 + lr;
            atomicMax(&apk[gc], f2ord(a));
            atomicMin(&ank[gc], f2ord(v));
        }
    }

    // ---- last-block loss reduction: mean(relu(ap - an + margin)) ----
    __shared__ int is_last;
    __threadfence();                          // mining atomics visible before ticket
    if (tid == 0) {
        unsigned old = atomicAdd(done, 1u);
        is_last = (old == (unsigned)(total - 1));
    }
    __syncthreads();
    if (is_last) {
        float s = 0.f;
        for (int i = tid; i < n; i += NTH) {
            float ap = ord2f(atomicAdd(&apk[i], 0u));   // coherent read
            float an = ord2f(atomicAdd(&ank[i], 0u));
            s += fmaxf(ap - an + MARGIN, 0.0f);
        }
        for (int off = 32; off; off >>= 1) s += __shfl_down(s, off);
        __shared__ float lws[4];
        if (lane == 0) lws[wid] = s;
        __syncthreads();
        if (tid == 0) out[0] = (lws[0] + lws[1] + lws[2] + lws[3]) / (float)n;
    }
}

extern "C" void kernel_launch(void* const* d_in, const int* in_sizes, int n_in,
                              void* d_out, int out_size, void* d_ws, size_t ws_size,
                              hipStream_t stream) {
    const float* X   = (const float*)d_in[0];
    const int*   tgt = (const int*)d_in[1];
    const int n = in_sizes[1];
    const int d = in_sizes[0] / n;

    float*    sq   = (float*)d_ws;
    unsigned* apk  = (unsigned*)((char*)d_ws + (size_t)n * 4);
    unsigned* ank  = apk + n;
    unsigned* done = (unsigned*)((char*)d_ws + (size_t)n * 12);
    unsigned short* Xb = (unsigned short*)((char*)d_ws + (size_t)n * 12 + 16);

    convert_kernel<<<n / 16, 256, 0, stream>>>(X, d, Xb, sq, apk, ank, done);
    const int nt = n / BMN;
    const int total = nt * (nt + 1) / 2;
    mfma_tile_kernel<<<total, NTH, 0, stream>>>(Xb, tgt, sq, apk, ank, done,
                                                (float*)d_out, n, d);
}

// Round 8
// 169.461 us; speedup vs baseline: 1.2296x; 1.2296x over previous
//
#include <hip/hip_runtime.h>

#define MARGIN  0.3f
#define NEG_INF -1e30f
#define POS_INF  1e30f

#define BMN 128
#define BK  64            // 64 fp8 elements = 64 bytes per row-chunk
#define NTH 256

typedef __attribute__((ext_vector_type(4))) float f32x4;

// async global->LDS, 16B per lane (dest linear in lane; source is per-lane)
#define GLOAD_LDS16(g, l) __builtin_amdgcn_global_load_lds(                      \
    (const __attribute__((address_space(1))) void*)(g),                          \
    (__attribute__((address_space(3))) void*)(l), 16, 0, 0)

// LDS byte offset for fp8 [128 rows][64 B] tile, rows paired into 128-B lines,
// 16B-granular XOR swizzle: <=2-way bank alias on 16-lane b64 frag reads (free).
__device__ __forceinline__ int LDSB(int row, int kb) {
    return ((row >> 1) << 7) + ((((row & 1) << 6) | kb) ^ (((row >> 1) & 7) << 4));
}

// ---- order-preserving float <-> uint mapping for atomic max/min ----
__device__ __forceinline__ unsigned f2ord(float f) {
    unsigned u = __float_as_uint(f);
    return (u & 0x80000000u) ? ~u : (u | 0x80000000u);
}
__device__ __forceinline__ float ord2f(unsigned u) {
    unsigned b = (u & 0x80000000u) ? (u ^ 0x80000000u) : ~u;
    return __uint_as_float(b);
}

// ---- kernel 1: fp32 -> fp8 e4m3 convert + row sum-of-squares + init acc ----
__global__ __launch_bounds__(256)
void convert_kernel(const float* __restrict__ X, int d,
                    unsigned char* __restrict__ X8,
                    float* __restrict__ sq,
                    unsigned* __restrict__ apk,
                    unsigned* __restrict__ ank,
                    unsigned* __restrict__ done) {
    const int row = blockIdx.x;
    const int tid = threadIdx.x;
    const float4* xr = (const float4*)(X + (size_t)row * d);
    float4 v0 = xr[tid * 2];
    float4 v1 = xr[tid * 2 + 1];
    float s = v0.x * v0.x + v0.y * v0.y + v0.z * v0.z + v0.w * v0.w
            + v1.x * v1.x + v1.y * v1.y + v1.z * v1.z + v1.w * v1.w;
    int dw0 = __builtin_amdgcn_cvt_pk_fp8_f32(v0.x, v0.y, 0, false);
    dw0     = __builtin_amdgcn_cvt_pk_fp8_f32(v0.z, v0.w, dw0, true);
    int dw1 = __builtin_amdgcn_cvt_pk_fp8_f32(v1.x, v1.y, 0, false);
    dw1     = __builtin_amdgcn_cvt_pk_fp8_f32(v1.z, v1.w, dw1, true);
    uint2 w; w.x = (unsigned)dw0; w.y = (unsigned)dw1;
    *(uint2*)(X8 + (size_t)row * d + tid * 8) = w;

    for (int off = 32; off; off >>= 1) s += __shfl_down(s, off);
    __shared__ float ws[4];
    int lane = tid & 63, wid = tid >> 6;
    if (lane == 0) ws[wid] = s;
    __syncthreads();
    if (tid == 0) {
        sq[row]  = ws[0] + ws[1] + ws[2] + ws[3];
        apk[row] = f2ord(NEG_INF);
        ank[row] = f2ord(POS_INF);
        if (row == 0) *done = 0u;
    }
}

// ---- kernel 2: fp8 MFMA Gram tile (upper-tri), dbuf BK=64, 4 blocks/CU,
//      fused mining + last-block loss reduction ----
__global__ __launch_bounds__(NTH, 4)
void mfma_tile_kernel(const unsigned char* __restrict__ X8,
                      const int* __restrict__ tgt,
                      const float* __restrict__ sq,
                      unsigned* __restrict__ apk, unsigned* __restrict__ ank,
                      unsigned* __restrict__ done, float* __restrict__ out,
                      int n, int d) {
    __shared__ char As[2][BMN * BK];         // 2 x 8 KB, pair-swizzled image
    __shared__ char Bs[2][BMN * BK];         // 2 x 8 KB
    __shared__ float srow_s[BMN], scol_s[BMN];
    __shared__ int   trow_s[BMN], tcol_s[BMN];

    const int nt = n / BMN;
    const int total = nt * (nt + 1) / 2;     // 528, divisible by 8
    const int cpx = total / 8;
    int b = (blockIdx.x % 8) * cpx + blockIdx.x / 8;
    int bi = 0, rem = b;
    for (; bi < nt; ++bi) { int cnt = nt - bi; if (rem < cnt) break; rem -= cnt; }
    const int bj = bi + rem;
    const int row0 = bi * BMN, col0 = bj * BMN;

    const int tid  = threadIdx.x;
    const int lane = tid & 63, wid = tid >> 6;
    const int wr = wid >> 1, wc = wid & 1;   // 2x2 waves, each 64x64 quadrant
    const int lr = lane & 15, lh = lane >> 4;

    if (tid < BMN) { srow_s[tid] = sq[row0 + tid]; trow_s[tid] = tgt[row0 + tid]; }
    else { int j = tid - BMN; scol_s[j] = sq[col0 + j]; tcol_s[j] = tgt[col0 + j]; }

    f32x4 acc[4][4];
#pragma unroll
    for (int m = 0; m < 4; ++m)
#pragma unroll
        for (int nn = 0; nn < 4; ++nn) acc[m][nn] = (f32x4){0.f, 0.f, 0.f, 0.f};

    const size_t dstride = (size_t)d;        // fp8 row stride in bytes
    const char* Arow = (const char*)X8 + (size_t)row0 * dstride;
    const char* Brow = (const char*)X8 + (size_t)col0 * dstride;

    // dest linear in lane; source pre-inverse-swizzled so LDS image matches LDSB()
#define STAGE(sel, kbyte)                                                        \
    do {                                                                         \
        _Pragma("unroll")                                                        \
        for (int it = 0; it < 2; ++it) {                                         \
            int p  = it * 4096 + tid * 16;                                       \
            int pr = p >> 7, q = p & 127;                                        \
            int u  = q ^ ((pr & 7) << 4);                                        \
            int r  = pr * 2 + (u >> 6);                                          \
            int kb = u & 63;                                                     \
            GLOAD_LDS16(Arow + (size_t)r * dstride + (kbyte) + kb,               \
                        (char*)As[sel] + p);                                     \
        }                                                                        \
        _Pragma("unroll")                                                        \
        for (int it = 0; it < 2; ++it) {                                         \
            int p  = it * 4096 + tid * 16;                                       \
            int pr = p >> 7, q = p & 127;                                        \
            int u  = q ^ ((pr & 7) << 4);                                        \
            int r  = pr * 2 + (u >> 6);                                          \
            int kb = u & 63;                                                     \
            GLOAD_LDS16(Brow + (size_t)r * dstride + (kbyte) + kb,               \
                        (char*)Bs[sel] + p);                                     \
        }                                                                        \
    } while (0)

    const int nt_k = d / BK;                 // 32 steps
    STAGE(0, 0);
    __syncthreads();                         // drain prologue + srow/scol visible
    int cur = 0;
    for (int t = 0; t < nt_k; ++t) {
        if (t + 1 < nt_k) STAGE(cur ^ 1, (t + 1) * BK);   // prefetch next K-tile
#pragma unroll
        for (int kk = 0; kk < 2; ++kk) {
            long af[4], bfr[4];
            const int kb2 = kk * 32 + lh * 8;    // byte offset along k (0..56)
#pragma unroll
            for (int m = 0; m < 4; ++m) {
                int ar = wr * 64 + m * 16 + lr;
                af[m] = *(const long*)((char*)As[cur] + LDSB(ar, kb2));
            }
#pragma unroll
            for (int nn = 0; nn < 4; ++nn) {
                int br = wc * 64 + nn * 16 + lr;
                bfr[nn] = *(const long*)((char*)Bs[cur] + LDSB(br, kb2));
            }
#pragma unroll
            for (int m = 0; m < 4; ++m)
#pragma unroll
                for (int nn = 0; nn < 4; ++nn)
                    acc[m][nn] = __builtin_amdgcn_mfma_f32_16x16x32_fp8_fp8(
                        af[m], bfr[nn], acc[m][nn], 0, 0, 0);
        }
        __syncthreads();                     // one barrier per K-step
        cur ^= 1;
    }
#undef STAGE

    // ---- epilogue: dist = sq_i + sq_j - 2*ip; mine rows AND cols ----
    float sc[4]; int tc[4];
#pragma unroll
    for (int nn = 0; nn < 4; ++nn) {
        int cl = wc * 64 + nn * 16 + lr;
        sc[nn] = scol_s[cl]; tc[nn] = tcol_s[cl];
    }
    float rap[4][4], ran[4][4], cap[4], can[4];
#pragma unroll
    for (int nn = 0; nn < 4; ++nn) { cap[nn] = NEG_INF; can[nn] = POS_INF; }
#pragma unroll
    for (int m = 0; m < 4; ++m)
#pragma unroll
        for (int j = 0; j < 4; ++j) { rap[m][j] = NEG_INF; ran[m][j] = POS_INF; }

#pragma unroll
    for (int m = 0; m < 4; ++m) {
#pragma unroll
        for (int j = 0; j < 4; ++j) {
            int rl = wr * 64 + m * 16 + lh * 4 + j;
            float sr = srow_s[rl];
            int   tr = trow_s[rl];
#pragma unroll
            for (int nn = 0; nn < 4; ++nn) {
                float dist = sr + sc[nn] - 2.0f * acc[m][nn][j];
                bool same = (tr == tc[nn]);
                float apv = same ? dist : NEG_INF;
                float anv = same ? POS_INF : dist;
                rap[m][j] = fmaxf(rap[m][j], apv);
                ran[m][j] = fminf(ran[m][j], anv);
                cap[nn]   = fmaxf(cap[nn], apv);
                can[nn]   = fminf(can[nn], anv);
            }
        }
    }
    // row mining: reduce over cols (lane bits 0..3), atomic per row
#pragma unroll
    for (int m = 0; m < 4; ++m) {
#pragma unroll
        for (int j = 0; j < 4; ++j) {
            float a = rap[m][j], v = ran[m][j];
#pragma unroll
            for (int off = 1; off < 16; off <<= 1) {
                a = fmaxf(a, __shfl_xor(a, off));
                v = fminf(v, __shfl_xor(v, off));
            }
            if (lr == 0) {
                int gr = row0 + wr * 64 + m * 16 + lh * 4 + j;
                atomicMax(&apk[gr], f2ord(a));
                atomicMin(&ank[gr], f2ord(v));
            }
        }
    }
    // col mining: reduce over rows (lane bits 4..5), atomic per col
#pragma unroll
    for (int nn = 0; nn < 4; ++nn) {
        float a = cap[nn], v = can[nn];
#pragma unroll
        for (int off = 16; off < 64; off <<= 1) {
            a = fmaxf(a, __shfl_xor(a, off));
            v = fminf(v, __shfl_xor(v, off));
        }
        if (lane < 16) {
            int gc = col0 + wc * 64 + nn * 16 + lr;
            atomicMax(&apk[gc], f2ord(a));
            atomicMin(&ank[gc], f2ord(v));
        }
    }

    // ---- last-block loss reduction: mean(relu(ap - an + margin)) ----
    __shared__ int is_last;
    __threadfence();                          // mining atomics visible before ticket
    if (tid == 0) {
        unsigned old = atomicAdd(done, 1u);
        is_last = (old == (unsigned)(total - 1));
    }
    __syncthreads();
    if (is_last) {
        float s = 0.f;
        for (int i = tid; i < n; i += NTH) {
            float ap = ord2f(atomicAdd(&apk[i], 0u));   // coherent read
            float an = ord2f(atomicAdd(&ank[i], 0u));
            s += fmaxf(ap - an + MARGIN, 0.0f);
        }
        for (int off = 32; off; off >>= 1) s += __shfl_down(s, off);
        __shared__ float lws[4];
        if (lane == 0) lws[wid] = s;
        __syncthreads();
        if (tid == 0) out[0] = (lws[0] + lws[1] + lws[2] + lws[3]) / (float)n;
    }
}

extern "C" void kernel_launch(void* const* d_in, const int* in_sizes, int n_in,
                              void* d_out, int out_size, void* d_ws, size_t ws_size,
                              hipStream_t stream) {
    const float* X   = (const float*)d_in[0];
    const int*   tgt = (const int*)d_in[1];
    const int n = in_sizes[1];
    const int d = in_sizes[0] / n;

    float*    sq   = (float*)d_ws;
    unsigned* apk  = (unsigned*)((char*)d_ws + (size_t)n * 4);
    unsigned* ank  = apk + n;
    unsigned* done = (unsigned*)((char*)d_ws + (size_t)n * 12);
    unsigned char* X8 = (unsigned char*)((char*)d_ws + (size_t)n * 12 + 16);

    convert_kernel<<<n, 256, 0, stream>>>(X, d, X8, sq, apk, ank, done);
    const int nt = n / BMN;
    const int total = nt * (nt + 1) / 2;
    mfma_tile_kernel<<<total, NTH, 0, stream>>>(X8, tgt, sq, apk, ank, done,
                                                (float*)d_out, n, d);
}